// Round 1
// baseline (535.277 us; speedup 1.0000x reference)
//
#include <hip/hip_runtime.h>

#define BB 64
#define LL 512
#define TT 52
#define START_TAG 50
#define END_TAG 51

// One block (1 wave, 64 lanes) per batch element.
// Lane j handles output tag j. trans column j held in registers.
// Partition vector in LDS (broadcast reads). Backpointers as bytes in LDS.
// FP order matches reference exactly: (f + trans[i][j]) + p[i], strict-> argmax
// ascending i == first-max-wins == jnp.argmax.
__launch_bounds__(64, 1)
__global__ void viterbi_kernel(const float* __restrict__ feats,
                               const int* __restrict__ mask,
                               const float* __restrict__ trans,
                               int* __restrict__ out) {
    const int b = blockIdx.x;
    const int lane = threadIdx.x;

    __shared__ float s_p[TT];
    __shared__ unsigned char s_bp[LL * TT];   // backpointers, 26624 B
    __shared__ int s_tags[LL];

    // ---- length = sum(mask[b, :]) (mask is 1 for t < n) ----
    int partial = 0;
    const int* mrow = mask + b * LL;
    #pragma unroll
    for (int k = 0; k < LL / 64; ++k) partial += mrow[lane + 64 * k];
    #pragma unroll
    for (int off = 32; off >= 1; off >>= 1) partial += __shfl_xor(partial, off, 64);
    const int n = partial;  // in [256, 512], identical across lanes

    // ---- transitions column j=lane into registers (coalesced per i) ----
    float c[TT];
    #pragma unroll
    for (int i = 0; i < TT; ++i) {
        c[i] = (lane < TT) ? trans[i * TT + lane] : 0.0f;
    }

    const float* frow = feats + (size_t)b * LL * TT;

    // ---- t = 0: partition0[j] = feats[b,0,j] + trans[START,j] ----
    if (lane < TT) {
        float f0 = frow[lane];
        s_p[lane] = f0 + c[START_TAG];
    }
    // zero-init tag buffer (covers positions [n, L-2] of the output)
    #pragma unroll
    for (int k = 0; k < LL / 64; ++k) s_tags[lane + 64 * k] = 0;
    __syncthreads();

    // software-pipelined feats load (n >= 256, so t=1 always exists)
    float f_next = (lane < TT) ? frow[1 * TT + lane] : 0.0f;

    // ---- forward: t = 1 .. n-1 ----
    for (int t = 1; t < n; ++t) {
        float f = f_next;
        int tn = (t + 1 < LL) ? (t + 1) : (LL - 1);
        f_next = (lane < TT) ? frow[tn * TT + lane] : 0.0f;

        // broadcast-read previous partition into regs (vectorizable ds_reads)
        float pv[TT];
        #pragma unroll
        for (int i = 0; i < TT; ++i) pv[i] = s_p[i];

        float best = -3.0e38f;
        int bi = 0;
        #pragma unroll
        for (int i = 0; i < TT; ++i) {
            float v = (f + c[i]) + pv[i];   // exact reference fp-order
            bool gt = v > best;             // strict > : first-max-wins
            best = gt ? v : best;
            bi   = gt ? i : bi;
        }
        __syncthreads();
        if (lane < TT) {
            s_p[lane] = best;                       // P_t[j]
            s_bp[t * TT + lane] = (unsigned char)bi; // bp_t[j]
        }
        __syncthreads();
    }

    // ---- pointer0 = argmax_i ( P_{n-1}[i] + trans[i, END] ) ----
    float lv = -3.0e38f;
    int li = lane;
    if (lane < TT) lv = s_p[lane] + trans[lane * TT + END_TAG];
    #pragma unroll
    for (int off = 32; off >= 1; off >>= 1) {
        float ov = __shfl_xor(lv, off, 64);
        int   oi = __shfl_xor(li, off, 64);
        if (ov > lv || (ov == lv && oi < li)) { lv = ov; li = oi; }
    }
    const int ptr0 = li;  // identical in all lanes

    // ---- backtrace (sequential pointer chase, lane 0) ----
    if (lane == 0) {
        s_tags[n - 1] = ptr0;
        s_tags[LL - 1] = ptr0;   // reference quirk: decode[L-1] = pointer0 always
        int ptr = ptr0;
        for (int t = n - 2; t >= 0; --t) {
            ptr = s_bp[(t + 1) * TT + ptr];
            s_tags[t] = ptr;
        }
    }
    __syncthreads();

    // ---- coalesced output write (int32) ----
    int* orow = out + b * LL;
    #pragma unroll
    for (int k = 0; k < LL / 64; ++k) orow[lane + 64 * k] = s_tags[lane + 64 * k];
}

extern "C" void kernel_launch(void* const* d_in, const int* in_sizes, int n_in,
                              void* d_out, int out_size, void* d_ws, size_t ws_size,
                              hipStream_t stream) {
    const float* feats = (const float*)d_in[0];
    const int*   mask  = (const int*)d_in[1];
    const float* trans = (const float*)d_in[2];
    int* out = (int*)d_out;
    viterbi_kernel<<<dim3(BB), dim3(64), 0, stream>>>(feats, mask, trans, out);
}

// Round 2
// 521.758 us; speedup vs baseline: 1.0259x; 1.0259x over previous
//
#include <hip/hip_runtime.h>

#define BB 64
#define LL 512
#define TT 52
#define START_TAG 50
#define END_TAG 51

// One block = ONE wave (64 lanes) per batch element. Lane j owns tag j.
// Single-wave workgroup => no __syncthreads needed: lanes execute in lockstep
// and same-wave DS ops are processed in order by the LDS pipeline. asm memory
// clobbers pin compiler ordering of the LDS write->read sequence.
// FP order matches reference exactly: (f + trans[i][j]) + p[i]; argmax via
// contiguous-range tree with take-left-on-tie == first-max-wins == jnp.argmax.
__launch_bounds__(64, 1)
__global__ void viterbi_kernel(const float* __restrict__ feats,
                               const int* __restrict__ mask,
                               const float* __restrict__ trans,
                               int* __restrict__ out) {
    const int b = blockIdx.x;
    const int lane = threadIdx.x;

    __shared__ __align__(16) float s_p[56];       // 52 used, padded for float4
    __shared__ unsigned char s_bp[LL * TT];       // backpointers, 26624 B
    __shared__ int s_tags[LL];

    // ---- length = sum(mask[b, :]) ----
    int partial = 0;
    const int* mrow = mask + b * LL;
    #pragma unroll
    for (int k = 0; k < LL / 64; ++k) partial += mrow[lane + 64 * k];
    #pragma unroll
    for (int off = 32; off >= 1; off >>= 1) partial += __shfl_xor(partial, off, 64);
    const int n = partial;  // in [256, 512], uniform across lanes

    // ---- transitions column j=lane into registers ----
    float c[TT];
    #pragma unroll
    for (int i = 0; i < TT; ++i)
        c[i] = (lane < TT) ? trans[i * TT + lane] : 0.0f;

    const float* frow = feats + (size_t)b * LL * TT;

    // ---- t = 0 ----
    if (lane < TT) s_p[lane] = frow[lane] + c[START_TAG];
    #pragma unroll
    for (int k = 0; k < LL / 64; ++k) s_tags[lane + 64 * k] = 0;
    __asm__ __volatile__("" ::: "memory");

    // one-step-ahead feats prefetch (n >= 2 always; lengths in [256,512])
    float f_next = (lane < TT) ? frow[TT + lane] : 0.0f;

    // ---- forward: t = 1 .. n-1 (no barriers; wave-synchronous) ----
    for (int t = 1; t < n; ++t) {
        float f = f_next;
        int tn = (t + 1 < LL) ? (t + 1) : (LL - 1);   // clamp; value unused when t+1>=n
        f_next = (lane < TT) ? frow[tn * TT + lane] : 0.0f;

        // broadcast-read previous partition: 13 x ds_read_b128, conflict-free
        float pv[TT];
        #pragma unroll
        for (int k = 0; k < 13; ++k) {
            float4 q = ((const float4*)s_p)[k];
            pv[4 * k + 0] = q.x; pv[4 * k + 1] = q.y;
            pv[4 * k + 2] = q.z; pv[4 * k + 3] = q.w;
        }

        // candidates, exact reference fp order
        float bv[TT]; int bid[TT];
        #pragma unroll
        for (int i = 0; i < TT; ++i) { bv[i] = (f + c[i]) + pv[i]; bid[i] = i; }

        // tree argmax over contiguous ranges, take-left-on-tie (depth 6)
        #pragma unroll
        for (int s = 1; s < TT; s <<= 1) {
            #pragma unroll
            for (int i = 0; i + s < TT; i += 2 * s) {
                bool gt = bv[i + s] > bv[i];
                bv[i]  = gt ? bv[i + s] : bv[i];
                bid[i] = gt ? bid[i + s] : bid[i];
            }
        }

        if (lane < TT) {
            s_p[lane] = bv[0];
            s_bp[t * TT + lane] = (unsigned char)bid[0];
        }
        __asm__ __volatile__("" ::: "memory");
    }

    // ---- pointer0 = argmax_i ( P_{n-1}[i] + trans[i, END] ), min-index tie ----
    float lv = -3.0e38f;
    int li = lane;
    if (lane < TT) lv = s_p[lane] + trans[lane * TT + END_TAG];
    #pragma unroll
    for (int off = 32; off >= 1; off >>= 1) {
        float ov = __shfl_xor(lv, off, 64);
        int   oi = __shfl_xor(li, off, 64);
        if (ov > lv || (ov == lv && oi < li)) { lv = ov; li = oi; }
    }
    const int ptr0 = li;  // uniform

    // ---- backtrace (sequential pointer chase, lane 0) ----
    if (lane == 0) {
        s_tags[n - 1] = ptr0;
        s_tags[LL - 1] = ptr0;   // reference quirk: decode[L-1] = pointer0 always
        int ptr = ptr0;
        for (int t = n - 2; t >= 0; --t) {
            ptr = s_bp[(t + 1) * TT + ptr];
            s_tags[t] = ptr;
        }
    }
    __asm__ __volatile__("" ::: "memory");

    // ---- coalesced output write ----
    int* orow = out + b * LL;
    #pragma unroll
    for (int k = 0; k < LL / 64; ++k) orow[lane + 64 * k] = s_tags[lane + 64 * k];
}

extern "C" void kernel_launch(void* const* d_in, const int* in_sizes, int n_in,
                              void* d_out, int out_size, void* d_ws, size_t ws_size,
                              hipStream_t stream) {
    const float* feats = (const float*)d_in[0];
    const int*   mask  = (const int*)d_in[1];
    const float* trans = (const float*)d_in[2];
    int* out = (int*)d_out;
    viterbi_kernel<<<dim3(BB), dim3(64), 0, stream>>>(feats, mask, trans, out);
}

// Round 3
// 496.821 us; speedup vs baseline: 1.0774x; 1.0502x over previous
//
#include <hip/hip_runtime.h>

#define BB 64
#define LL 512
#define TT 52
#define START_TAG 50
#define END_TAG 51

// One block = ONE wave (64 lanes) per batch element. Lane j owns tag j.
// Wave-synchronous: no barriers; LDS pipe is in-order within a wave, and
// compiler alias analysis (dynamic-index store to s_p vs const-index loads)
// preserves program order of the s_p write -> read chain. No asm clobbers,
// so the scheduler may software-pipeline LDS reads across substeps.
// feats loads use a 4-deep prefetch ring (t-loop unrolled x4) so global-load
// latency (~900 cyc HBM / ~500 L3) is fully hidden by ~4 substeps of slack.
// FP order matches reference exactly: (f + trans[i][j]) + P[i]; argmax via
// contiguous-range tree, take-left-on-tie == first-max-wins == jnp.argmax.
__launch_bounds__(64, 1)
__global__ void viterbi_kernel(const float* __restrict__ feats,
                               const int* __restrict__ mask,
                               const float* __restrict__ trans,
                               int* __restrict__ out) {
    const int b = blockIdx.x;
    const int lane = threadIdx.x;

    __shared__ __align__(16) float s_p[56];       // 52 used, padded for float4
    __shared__ unsigned char s_bp[LL * TT];       // backpointers, 26624 B
    __shared__ int s_tags[LL];

    // ---- length = sum(mask[b, :]) ----
    int partial = 0;
    const int* mrow = mask + b * LL;
    #pragma unroll
    for (int k = 0; k < LL / 64; ++k) partial += mrow[lane + 64 * k];
    #pragma unroll
    for (int off = 32; off >= 1; off >>= 1) partial += __shfl_xor(partial, off, 64);
    const int n = partial;  // in [256, 512], uniform across lanes

    // ---- transitions column j=lane into registers ----
    float c[TT];
    #pragma unroll
    for (int i = 0; i < TT; ++i)
        c[i] = (lane < TT) ? trans[i * TT + lane] : 0.0f;

    const float* frow = feats + (size_t)b * LL * TT;

    // ---- t = 0 ----
    if (lane < TT) s_p[lane] = frow[lane] + c[START_TAG];
    #pragma unroll
    for (int k = 0; k < LL / 64; ++k) s_tags[lane + 64 * k] = 0;

    // ---- one Viterbi substep (exact reference fp order) ----
    auto substep = [&](int t, float f) {
        // broadcast-read previous partition: 13 x ds_read_b128, conflict-free
        float pv[TT];
        #pragma unroll
        for (int k = 0; k < 13; ++k) {
            float4 q = ((const float4*)s_p)[k];
            pv[4 * k + 0] = q.x; pv[4 * k + 1] = q.y;
            pv[4 * k + 2] = q.z; pv[4 * k + 3] = q.w;
        }
        float bv[TT]; int bid[TT];
        #pragma unroll
        for (int i = 0; i < TT; ++i) { bv[i] = (f + c[i]) + pv[i]; bid[i] = i; }
        // tree argmax over contiguous ranges, take-left-on-tie (depth 6)
        #pragma unroll
        for (int s = 1; s < TT; s <<= 1) {
            #pragma unroll
            for (int i = 0; i + s < TT; i += 2 * s) {
                bool gt = bv[i + s] > bv[i];
                bv[i]  = gt ? bv[i + s] : bv[i];
                bid[i] = gt ? bid[i + s] : bid[i];
            }
        }
        if (lane < TT) {
            s_p[lane] = bv[0];                        // next substep reads this
            s_bp[t * TT + lane] = (unsigned char)bid[0];
        }
    };

    // ---- prefetch ring: fr[d] = feats row for step tcur + d ----
    float fr[4];
    #pragma unroll
    for (int d = 0; d < 4; ++d) {
        int tt = 1 + d; if (tt > LL - 1) tt = LL - 1;
        fr[d] = (lane < TT) ? frow[tt * TT + lane] : 0.0f;
    }

    // ---- forward main loop, unrolled x4 (t = 1 .. ) ----
    int t = 1;
    for (; t + 3 < n; t += 4) {
        #pragma unroll
        for (int d = 0; d < 4; ++d) {
            float f = fr[d];
            int tt = t + d + 4; if (tt > LL - 1) tt = LL - 1;
            fr[d] = (lane < TT) ? frow[tt * TT + lane] : 0.0f;  // refill ring
            substep(t + d, f);
        }
    }
    // ---- tail (<= 3 steps); ring still holds rows t..t+3 ----
    for (int d = 0; t < n; ++t, ++d) {
        substep(t, fr[d]);
    }

    // ---- pointer0 = argmax_i ( P_{n-1}[i] + trans[i, END] ), min-index tie ----
    float lv = -3.0e38f;
    int li = lane;
    if (lane < TT) lv = s_p[lane] + trans[lane * TT + END_TAG];
    #pragma unroll
    for (int off = 32; off >= 1; off >>= 1) {
        float ov = __shfl_xor(lv, off, 64);
        int   oi = __shfl_xor(li, off, 64);
        if (ov > lv || (ov == lv && oi < li)) { lv = ov; li = oi; }
    }
    const int ptr0 = li;  // uniform

    // ---- backtrace (sequential pointer chase, lane 0) ----
    if (lane == 0) {
        s_tags[n - 1] = ptr0;
        s_tags[LL - 1] = ptr0;   // reference quirk: decode[L-1] = pointer0 always
        int ptr = ptr0;
        for (int tt = n - 2; tt >= 0; --tt) {
            ptr = s_bp[(tt + 1) * TT + ptr];
            s_tags[tt] = ptr;
        }
    }

    // ---- coalesced output write ----
    int* orow = out + b * LL;
    #pragma unroll
    for (int k = 0; k < LL / 64; ++k) orow[lane + 64 * k] = s_tags[lane + 64 * k];
}

extern "C" void kernel_launch(void* const* d_in, const int* in_sizes, int n_in,
                              void* d_out, int out_size, void* d_ws, size_t ws_size,
                              hipStream_t stream) {
    const float* feats = (const float*)d_in[0];
    const int*   mask  = (const int*)d_in[1];
    const float* trans = (const float*)d_in[2];
    int* out = (int*)d_out;
    viterbi_kernel<<<dim3(BB), dim3(64), 0, stream>>>(feats, mask, trans, out);
}

// Round 4
// 316.050 us; speedup vs baseline: 1.6936x; 1.5720x over previous
//
#include <hip/hip_runtime.h>

#define BB 64
#define LL 512
#define TT 52
#define START_TAG 50
#define END_TAG 51

// Block = 256 threads = 4 waves per batch element. Wave w owns the i-range
// [13w, 13w+13). Lane j (j<52) of EVERY wave holds the combined P[j] in a
// register. Per step: readlane-broadcast P over the wave's i-range, partial
// max-plus reduce (13 wide), one ds_write_b64 partial, ONE barrier,
// 4x ds_read_b64 + ascending-w combine -> new P[j] in-register everywhere.
// Partials double-buffered (loop unrolled x2) to avoid a second barrier.
// Exact-fp: candidate value is the reference's (f + c[i]) + P[i]; per-wave
// tree is take-left-on-tie over ascending q, cross-wave combine is strict >
// ascending w => global first-max-wins == jnp.argmax. P moves as bit-copies.
__launch_bounds__(256, 1)
__global__ void viterbi_kernel(const float* __restrict__ feats,
                               const int* __restrict__ mask,
                               const float* __restrict__ trans,
                               int* __restrict__ out) {
    const int b    = blockIdx.x;
    const int tid  = threadIdx.x;
    const int lane = tid & 63;
    const int w    = tid >> 6;
    const int wbase = w * 13;

    __shared__ unsigned long long s_part[2][64 * 5 + 8]; // [buf][j*5 + w], padded stride-5 (2-way max)
    __shared__ unsigned char s_bp[LL * TT];              // backpointers (26624 B)
    __shared__ int s_tags[LL];

    // ---- length n = sum(mask[b,:]) (redundant per wave) ----
    int partial = 0;
    const int* mrow = mask + b * LL;
    #pragma unroll
    for (int k = 0; k < LL / 64; ++k) partial += mrow[lane + 64 * k];
    #pragma unroll
    for (int off = 32; off >= 1; off >>= 1) partial += __shfl_xor(partial, off, 64);
    const int n = partial;  // uniform, in [256, 512]

    // ---- per-wave transition slice: creg[q] = trans[(13w+q)][lane] ----
    float creg[13];
    #pragma unroll
    for (int q = 0; q < 13; ++q)
        creg[q] = (lane < TT) ? trans[(wbase + q) * TT + lane] : 0.0f;
    // end-transition column, preloaded for pointer0
    const float tE = (lane < TT) ? trans[lane * TT + END_TAG] : 0.0f;

    const float* frow = feats + (size_t)b * LL * TT;

    // ---- P0 in-register, every wave ----
    float bestP = (lane < TT) ? (frow[lane] + trans[START_TAG * TT + lane]) : -3.0e38f;

    // zero-init tags
    #pragma unroll
    for (int k = 0; k < LL / 256; ++k) s_tags[tid + 256 * k] = 0;

    const int slot = lane * 5 + w;   // partial slot for this (j=lane, w)

    // ---- one step ----
    auto step = [&](int t, int buf, float f) {
        // broadcast P over this wave's i-range (indices loop-invariant)
        float pv[13];
        #pragma unroll
        for (int q = 0; q < 13; ++q)
            pv[q] = __int_as_float(__builtin_amdgcn_readlane(__float_as_int(bestP), wbase + q));

        // candidates, exact reference fp order
        float bv[13]; int bq[13];
        #pragma unroll
        for (int q = 0; q < 13; ++q) { bv[q] = (f + creg[q]) + pv[q]; bq[q] = q; }
        // take-left-on-tie tree over 13
        #pragma unroll
        for (int s = 1; s < 13; s <<= 1) {
            #pragma unroll
            for (int i = 0; i + s < 13; i += 2 * s) {
                bool gt = bv[i + s] > bv[i];
                bv[i] = gt ? bv[i + s] : bv[i];
                bq[i] = gt ? bq[i + s] : bq[i];
            }
        }
        int pidx = wbase + bq[0];
        unsigned long long pk = ((unsigned long long)(unsigned)pidx << 32)
                              | (unsigned long long)(unsigned)__float_as_uint(bv[0]);
        s_part[buf][slot] = pk;
        __syncthreads();

        // combine ascending w (strict > keeps earliest range on ties)
        unsigned long long p0 = s_part[buf][lane * 5 + 0];
        unsigned long long p1 = s_part[buf][lane * 5 + 1];
        unsigned long long p2 = s_part[buf][lane * 5 + 2];
        unsigned long long p3 = s_part[buf][lane * 5 + 3];
        float cv = __uint_as_float((unsigned)p0); int ci = (int)(p0 >> 32);
        {
            float v1 = __uint_as_float((unsigned)p1); int i1 = (int)(p1 >> 32);
            bool gt = v1 > cv; cv = gt ? v1 : cv; ci = gt ? i1 : ci;
            float v2 = __uint_as_float((unsigned)p2); int i2 = (int)(p2 >> 32);
            gt = v2 > cv; cv = gt ? v2 : cv; ci = gt ? i2 : ci;
            float v3 = __uint_as_float((unsigned)p3); int i3 = (int)(p3 >> 32);
            gt = v3 > cv; cv = gt ? v3 : cv; ci = gt ? i3 : ci;
        }
        bestP = cv;                       // new P[lane], in-register, every wave
        if (tid < TT) s_bp[t * TT + tid] = (unsigned char)ci;  // wave0 stores bp
    };

    // ---- 2-deep feats prefetch (rows t=1,2 always exist: n >= 256) ----
    float fA = (lane < TT) ? frow[1 * TT + lane] : 0.0f;
    float fB = (lane < TT) ? frow[2 * TT + lane] : 0.0f;

    int t = 1;
    for (; t + 1 < n; t += 2) {
        {
            float f = fA;
            int tt = t + 2; if (tt > LL - 1) tt = LL - 1;
            fA = (lane < TT) ? frow[tt * TT + lane] : 0.0f;
            step(t, 0, f);
        }
        {
            float f = fB;
            int tt = t + 3; if (tt > LL - 1) tt = LL - 1;
            fB = (lane < TT) ? frow[tt * TT + lane] : 0.0f;
            step(t + 1, 1, f);
        }
    }
    if (t < n) step(t, 0, fA);   // tail (even n-1 count)

    // ---- pointer0 = argmax_i ( P_{n-1}[i] + trans[i,END] ), min-index tie ----
    float lv = (lane < TT) ? (bestP + tE) : -3.0e38f;
    int li = lane;
    #pragma unroll
    for (int off = 32; off >= 1; off >>= 1) {
        float ov = __shfl_xor(lv, off, 64);
        int   oi = __shfl_xor(li, off, 64);
        if (ov > lv || (ov == lv && oi < li)) { lv = ov; li = oi; }
    }
    const int ptr0 = li;   // uniform within each wave (all waves agree)

    // ---- backtrace (thread 0; same wave as bp writer => in-order LDS) ----
    __syncthreads();
    if (tid == 0) {
        s_tags[n - 1] = ptr0;
        s_tags[LL - 1] = ptr0;   // reference quirk: decode[L-1] = pointer0 always
        int ptr = ptr0;
        for (int tt = n - 2; tt >= 0; --tt) {
            ptr = s_bp[(tt + 1) * TT + ptr];
            s_tags[tt] = ptr;
        }
    }
    __syncthreads();

    // ---- coalesced output write ----
    int* orow = out + b * LL;
    #pragma unroll
    for (int k = 0; k < LL / 256; ++k) orow[tid + 256 * k] = s_tags[tid + 256 * k];
}

extern "C" void kernel_launch(void* const* d_in, const int* in_sizes, int n_in,
                              void* d_out, int out_size, void* d_ws, size_t ws_size,
                              hipStream_t stream) {
    const float* feats = (const float*)d_in[0];
    const int*   mask  = (const int*)d_in[1];
    const float* trans = (const float*)d_in[2];
    int* out = (int*)d_out;
    viterbi_kernel<<<dim3(BB), dim3(256), 0, stream>>>(feats, mask, trans, out);
}

// Round 5
// 293.161 us; speedup vs baseline: 1.8259x; 1.0781x over previous
//
#include <hip/hip_runtime.h>

#define BB 64
#define LL 512
#define TT 52
#define START_TAG 50
#define END_TAG 51

// Raw LDS-only barrier: orders LDS (lgkmcnt) and rendezvouses waves WITHOUT
// draining outstanding global loads (vmcnt). __syncthreads() would emit
// s_waitcnt vmcnt(0) before s_barrier, putting the feats prefetch latency on
// the critical path of every step (the R4 stall).
__device__ __forceinline__ void lds_barrier() {
    __asm__ __volatile__("s_waitcnt lgkmcnt(0)\n\ts_barrier" ::: "memory");
}

// Block = 256 threads = 4 waves per batch element. Wave w owns the i-range
// [13w, 13w+13). Lane j (j<52) of EVERY wave holds the combined P[j] in a
// register. Per step: readlane-broadcast P over the wave's i-range, partial
// max-plus reduce (13 wide), one ds_write_b64 partial, ONE lds_barrier,
// 4x ds_read_b64 + ascending-w combine -> new P[j] in-register everywhere.
// Partials double-buffered (consecutive steps alternate buf) so one barrier
// per step suffices. feats prefetched 4 steps ahead in registers; with the
// vmcnt-preserving barrier those loads stay in flight across steps.
// Exact-fp: candidate value is the reference's (f + c[i]) + P[i]; per-wave
// tree is take-left-on-tie over ascending q, cross-wave combine is strict >
// ascending w => global first-max-wins == jnp.argmax. P moves as bit-copies.
__launch_bounds__(256, 1)
__global__ void viterbi_kernel(const float* __restrict__ feats,
                               const int* __restrict__ mask,
                               const float* __restrict__ trans,
                               int* __restrict__ out) {
    const int b    = blockIdx.x;
    const int tid  = threadIdx.x;
    const int lane = tid & 63;
    const int w    = tid >> 6;
    const int wbase = w * 13;

    __shared__ unsigned long long s_part[2][64 * 5 + 8]; // [buf][j*5 + w]
    __shared__ unsigned char s_bp[LL * TT];              // backpointers (26624 B)
    __shared__ int s_tags[LL];

    // ---- length n = sum(mask[b,:]) (redundant per wave) ----
    int partial = 0;
    const int* mrow = mask + b * LL;
    #pragma unroll
    for (int k = 0; k < LL / 64; ++k) partial += mrow[lane + 64 * k];
    #pragma unroll
    for (int off = 32; off >= 1; off >>= 1) partial += __shfl_xor(partial, off, 64);
    const int n = partial;  // uniform, in [256, 512]

    // ---- per-wave transition slice: creg[q] = trans[(13w+q)][lane] ----
    float creg[13];
    #pragma unroll
    for (int q = 0; q < 13; ++q)
        creg[q] = (lane < TT) ? trans[(wbase + q) * TT + lane] : 0.0f;
    const float tE = (lane < TT) ? trans[lane * TT + END_TAG] : 0.0f;

    const float* frow = feats + (size_t)b * LL * TT;

    // ---- P0 in-register, every wave ----
    float bestP = (lane < TT) ? (frow[lane] + trans[START_TAG * TT + lane]) : -3.0e38f;

    // zero-init tags
    #pragma unroll
    for (int k = 0; k < LL / 256; ++k) s_tags[tid + 256 * k] = 0;

    const int slot = lane * 5 + w;

    // ---- one step ----
    auto step = [&](int t, int buf, float f) {
        // broadcast P over this wave's i-range (SGPR broadcasts)
        float pv[13];
        #pragma unroll
        for (int q = 0; q < 13; ++q)
            pv[q] = __int_as_float(__builtin_amdgcn_readlane(__float_as_int(bestP), wbase + q));

        // candidates, exact reference fp order
        float bv[13]; int bq[13];
        #pragma unroll
        for (int q = 0; q < 13; ++q) { bv[q] = (f + creg[q]) + pv[q]; bq[q] = q; }
        // take-left-on-tie tree over 13
        #pragma unroll
        for (int s = 1; s < 13; s <<= 1) {
            #pragma unroll
            for (int i = 0; i + s < 13; i += 2 * s) {
                bool gt = bv[i + s] > bv[i];
                bv[i] = gt ? bv[i + s] : bv[i];
                bq[i] = gt ? bq[i + s] : bq[i];
            }
        }
        int pidx = wbase + bq[0];
        unsigned long long pk = ((unsigned long long)(unsigned)pidx << 32)
                              | (unsigned long long)(unsigned)__float_as_uint(bv[0]);
        s_part[buf][slot] = pk;
        lds_barrier();   // LDS-order + rendezvous; vmcnt stays in flight

        // combine ascending w (strict > keeps earliest range on ties)
        unsigned long long p0 = s_part[buf][lane * 5 + 0];
        unsigned long long p1 = s_part[buf][lane * 5 + 1];
        unsigned long long p2 = s_part[buf][lane * 5 + 2];
        unsigned long long p3 = s_part[buf][lane * 5 + 3];
        float cv = __uint_as_float((unsigned)p0); int ci = (int)(p0 >> 32);
        {
            float v1 = __uint_as_float((unsigned)p1); int i1 = (int)(p1 >> 32);
            bool gt = v1 > cv; cv = gt ? v1 : cv; ci = gt ? i1 : ci;
            float v2 = __uint_as_float((unsigned)p2); int i2 = (int)(p2 >> 32);
            gt = v2 > cv; cv = gt ? v2 : cv; ci = gt ? i2 : ci;
            float v3 = __uint_as_float((unsigned)p3); int i3 = (int)(p3 >> 32);
            gt = v3 > cv; cv = gt ? v3 : cv; ci = gt ? i3 : ci;
        }
        bestP = cv;                       // new P[lane], in-register, every wave
        if (tid < TT) s_bp[t * TT + tid] = (unsigned char)ci;  // wave0 stores bp
    };

    // ---- 4-deep feats prefetch ring ----
    float fr[4];
    #pragma unroll
    for (int d = 0; d < 4; ++d) {
        int tt = 1 + d; if (tt > LL - 1) tt = LL - 1;
        fr[d] = (lane < TT) ? frow[tt * TT + lane] : 0.0f;
    }

    int t = 1;
    for (; t + 3 < n; t += 4) {
        #pragma unroll
        for (int d = 0; d < 4; ++d) {
            float f = fr[d];
            int tt = t + d + 4; if (tt > LL - 1) tt = LL - 1;
            fr[d] = (lane < TT) ? frow[tt * TT + lane] : 0.0f;  // refill ring
            step(t + d, d & 1, f);
        }
    }
    // tail (<= 3 steps); buffer parity continues 0,1,0 after main's ...,1
    for (int d = 0; t < n; ++t, ++d) {
        step(t, d & 1, fr[d]);
    }

    // ---- pointer0 = argmax_i ( P_{n-1}[i] + trans[i,END] ), min-index tie ----
    float lv = (lane < TT) ? (bestP + tE) : -3.0e38f;
    int li = lane;
    #pragma unroll
    for (int off = 32; off >= 1; off >>= 1) {
        float ov = __shfl_xor(lv, off, 64);
        int   oi = __shfl_xor(li, off, 64);
        if (ov > lv || (ov == lv && oi < li)) { lv = ov; li = oi; }
    }
    const int ptr0 = li;   // uniform (all waves agree)

    __syncthreads();
    // ---- backtrace (thread 0) ----
    if (tid == 0) {
        s_tags[n - 1] = ptr0;
        s_tags[LL - 1] = ptr0;   // reference quirk: decode[L-1] = pointer0 always
        int ptr = ptr0;
        for (int tt = n - 2; tt >= 0; --tt) {
            ptr = s_bp[(tt + 1) * TT + ptr];
            s_tags[tt] = ptr;
        }
    }
    __syncthreads();

    // ---- coalesced output write ----
    int* orow = out + b * LL;
    #pragma unroll
    for (int k = 0; k < LL / 256; ++k) orow[tid + 256 * k] = s_tags[tid + 256 * k];
}

extern "C" void kernel_launch(void* const* d_in, const int* in_sizes, int n_in,
                              void* d_out, int out_size, void* d_ws, size_t ws_size,
                              hipStream_t stream) {
    const float* feats = (const float*)d_in[0];
    const int*   mask  = (const int*)d_in[1];
    const float* trans = (const float*)d_in[2];
    int* out = (int*)d_out;
    viterbi_kernel<<<dim3(BB), dim3(256), 0, stream>>>(feats, mask, trans, out);
}

// Round 6
// 289.910 us; speedup vs baseline: 1.8464x; 1.0112x over previous
//
#include <hip/hip_runtime.h>

#define BB 64
#define LL 512
#define TT 52
#define START_TAG 50
#define END_TAG 51

// Raw LDS-only barrier: orders LDS (lgkmcnt) and rendezvouses waves WITHOUT
// draining outstanding global loads (vmcnt), so feats prefetch stays in flight.
__device__ __forceinline__ void lds_barrier() {
    __asm__ __volatile__("s_waitcnt lgkmcnt(0)\n\ts_barrier" ::: "memory");
}

__device__ __forceinline__ unsigned umin32(unsigned a, unsigned b) { return a < b ? a : b; }

// Block = 256 threads = 4 waves per batch element. Wave w owns i in
// [13w, 13w+13). Lane j (<52) of EVERY wave holds combined P[j] in a register.
// Per step: readlane-broadcast P over the wave's i-range, VCC-FREE partial
// argmax (v_max3 value tree + xor/min/key index extraction -- no v_cmp/VCC
// serialization), one ds_write_b64 partial, one lds_barrier, 4x ds_read_b64 +
// VCC-free combine -> new P[j] in-register everywhere. Double-buffered
// partials; feats in a 4-deep register prefetch ring.
// Exactness: candidate value is the reference's (f + c[i]) + P[i] bit-exact;
// float max is order-independent; index extraction picks the smallest i whose
// value bits equal the max bits == first-max-wins == jnp.argmax (fp ties have
// identical bits; +-0 maxima are probability-zero with continuous data).
// Backtrace: 8-chunk two-phase parallel pointer chase instead of 511 serial
// ~120-cyc dependent LDS loads.
__launch_bounds__(256, 1)
__global__ void viterbi_kernel(const float* __restrict__ feats,
                               const int* __restrict__ mask,
                               const float* __restrict__ trans,
                               int* __restrict__ out) {
    const int b    = blockIdx.x;
    const int tid  = threadIdx.x;
    const int lane = tid & 63;
    const int w    = tid >> 6;
    const int wbase = w * 13;

    __shared__ unsigned long long s_part[2][64 * 5 + 8]; // [buf][j*5 + w]
    __shared__ unsigned char s_bp[LL * TT];              // backpointers (26624 B)
    __shared__ int s_tags[LL];
    __shared__ unsigned char s_map[8 * 52];              // chunk composition maps
    __shared__ int s_ent[8];                             // chunk entry tags

    // ---- length n = sum(mask[b,:]) ----
    int partial = 0;
    const int* mrow = mask + b * LL;
    #pragma unroll
    for (int k = 0; k < LL / 64; ++k) partial += mrow[lane + 64 * k];
    #pragma unroll
    for (int off = 32; off >= 1; off >>= 1) partial += __shfl_xor(partial, off, 64);
    const int n = partial;  // uniform, in [256, 512]

    // ---- per-wave transition slice: creg[q] = trans[(13w+q)][lane] ----
    float creg[13];
    #pragma unroll
    for (int q = 0; q < 13; ++q)
        creg[q] = (lane < TT) ? trans[(wbase + q) * TT + lane] : 0.0f;
    const float tE = (lane < TT) ? trans[lane * TT + END_TAG] : 0.0f;

    const float* frow = feats + (size_t)b * LL * TT;

    // ---- P0 in-register, every wave ----
    float bestP = (lane < TT) ? (frow[lane] + trans[START_TAG * TT + lane]) : -3.0e38f;

    // zero-init tags
    #pragma unroll
    for (int k = 0; k < LL / 256; ++k) s_tags[tid + 256 * k] = 0;

    const int slot = lane * 5 + w;

    // ---- one step (VCC-free argmax) ----
    auto step = [&](int t, int buf, float f) {
        // tmp = f + c[i]: independent of P -> schedulable early
        float tmp[13];
        #pragma unroll
        for (int q = 0; q < 13; ++q) tmp[q] = f + creg[q];

        // broadcast P over this wave's i-range (SGPR broadcasts)
        float bv[13];
        #pragma unroll
        for (int q = 0; q < 13; ++q) {
            float pq = __int_as_float(__builtin_amdgcn_readlane(__float_as_int(bestP), wbase + q));
            bv[q] = tmp[q] + pq;                       // exact reference fp order
        }

        // value max: order-independent, maps to v_max3_f32 (no VCC)
        float m0 = fmaxf(fmaxf(bv[0], bv[1]), bv[2]);
        float m1 = fmaxf(fmaxf(bv[3], bv[4]), bv[5]);
        float m2 = fmaxf(fmaxf(bv[6], bv[7]), bv[8]);
        float m3 = fmaxf(fmaxf(bv[9], bv[10]), bv[11]);
        float M  = fmaxf(fmaxf(fmaxf(m0, m1), fmaxf(m2, m3)), bv[12]);

        // index extraction: smallest q with bits(bv[q])==bits(M)  (no VCC)
        unsigned kk[13];
        #pragma unroll
        for (int q = 0; q < 13; ++q) {
            unsigned e  = __float_as_uint(bv[q]) ^ __float_as_uint(M);
            unsigned nz = umin32(e, 1u);               // v_min_u32
            kk[q] = (nz << 6) | (unsigned)q;
        }
        unsigned k0 = umin32(umin32(kk[0], kk[1]), kk[2]);
        unsigned k1 = umin32(umin32(kk[3], kk[4]), kk[5]);
        unsigned k2 = umin32(umin32(kk[6], kk[7]), kk[8]);
        unsigned k3 = umin32(umin32(kk[9], kk[10]), kk[11]);
        unsigned km = umin32(umin32(umin32(k0, k1), umin32(k2, k3)), kk[12]);
        unsigned pidx = (unsigned)wbase + (km & 63u);

        unsigned long long pk = ((unsigned long long)pidx << 32)
                              | (unsigned long long)__float_as_uint(M);
        s_part[buf][slot] = pk;
        lds_barrier();   // LDS-order + rendezvous; vmcnt stays in flight

        // cross-wave combine (VCC-free); disjoint ascending i-ranges =>
        // min-key on bit-equal ties == earliest global i
        unsigned long long p0 = s_part[buf][lane * 5 + 0];
        unsigned long long p1 = s_part[buf][lane * 5 + 1];
        unsigned long long p2 = s_part[buf][lane * 5 + 2];
        unsigned long long p3 = s_part[buf][lane * 5 + 3];
        float v0 = __uint_as_float((unsigned)p0);
        float v1 = __uint_as_float((unsigned)p1);
        float v2 = __uint_as_float((unsigned)p2);
        float v3 = __uint_as_float((unsigned)p3);
        float cv = fmaxf(fmaxf(v0, v1), fmaxf(v2, v3));
        unsigned cb = __float_as_uint(cv);
        unsigned c0 = (umin32(__float_as_uint(v0) ^ cb, 1u) << 6) | (unsigned)(p0 >> 32);
        unsigned c1 = (umin32(__float_as_uint(v1) ^ cb, 1u) << 6) | (unsigned)(p1 >> 32);
        unsigned c2 = (umin32(__float_as_uint(v2) ^ cb, 1u) << 6) | (unsigned)(p2 >> 32);
        unsigned c3 = (umin32(__float_as_uint(v3) ^ cb, 1u) << 6) | (unsigned)(p3 >> 32);
        unsigned ci = umin32(umin32(c0, c1), umin32(c2, c3)) & 63u;

        bestP = cv;                        // new P[lane], in-register, every wave
        if (tid < TT) s_bp[t * TT + tid] = (unsigned char)ci;
    };

    // ---- 4-deep feats prefetch ring ----
    float fr[4];
    #pragma unroll
    for (int d = 0; d < 4; ++d) {
        int tt = 1 + d; if (tt > LL - 1) tt = LL - 1;
        fr[d] = (lane < TT) ? frow[tt * TT + lane] : 0.0f;
    }

    int t = 1;
    for (; t + 3 < n; t += 4) {
        #pragma unroll
        for (int d = 0; d < 4; ++d) {
            float f = fr[d];
            int tt = t + d + 4; if (tt > LL - 1) tt = LL - 1;
            fr[d] = (lane < TT) ? frow[tt * TT + lane] : 0.0f;  // refill ring
            step(t + d, d & 1, f);
        }
    }
    for (int d = 0; t < n; ++t, ++d) step(t, d & 1, fr[d]);     // tail <= 3

    // ---- pointer0 = argmax_i ( P_{n-1}[i] + trans[i,END] ), min-index tie ----
    float lv = (lane < TT) ? (bestP + tE) : -3.0e38f;
    int li = lane;
    #pragma unroll
    for (int off = 32; off >= 1; off >>= 1) {
        float ov = __shfl_xor(lv, off, 64);
        int   oi = __shfl_xor(li, off, 64);
        if (ov > lv || (ov == lv && oi < li)) { lv = ov; li = oi; }
    }
    const int ptr0 = li;   // uniform (all waves agree)

    __syncthreads();

    // ---- backtrace: 8-chunk two-phase parallel pointer chase ----
    // walk index s in [0, W): reads bp row (n-1-s), produces tag at t=n-2-s.
    const int W  = n - 1;
    const int Sc = (W + 7) >> 3;
    {
        // phase 1: 416 walkers (chunk k 0..7, tag y 0..51); 2 per thread,
        // interleaved so the two dependent-load chains overlap in flight.
        int v0 = tid;                 // < 416 always
        int k0 = v0 / 52, y0 = v0 - k0 * 52;
        int v1 = tid + 256;
        bool a1 = (v1 < 416);
        int k1 = a1 ? v1 / 52 : 7, y1 = a1 ? (v1 - k1 * 52) : 0;
        int s0a = k0 * Sc, s1a = min(s0a + Sc, W);
        int s0b = k1 * Sc, s1b = min(s0b + Sc, W);
        int xa = y0, xb = y1;
        for (int s = 0; s < Sc; ++s) {
            int ga = s0a + s, gb = s0b + s;
            if (ga < s1a) xa = s_bp[(n - 1 - ga) * TT + xa];
            if (gb < s1b) xb = s_bp[(n - 1 - gb) * TT + xb];
        }
        s_map[k0 * 52 + y0] = (unsigned char)xa;
        if (a1) s_map[k1 * 52 + y1] = (unsigned char)xb;
    }
    __syncthreads();
    if (tid == 0) {
        // chain chunk maps: entry tag of each chunk
        int e = ptr0; s_ent[0] = e;
        #pragma unroll
        for (int k = 1; k < 8; ++k) { e = s_map[(k - 1) * 52 + e]; s_ent[k] = e; }
        s_tags[n - 1] = ptr0;
        s_tags[LL - 1] = ptr0;   // reference quirk: decode[L-1] = pointer0 always
    }
    __syncthreads();
    if (tid < 8) {
        // phase 2: replay 8 chunks concurrently (one lane each)
        int k = tid;
        int x = s_ent[k];
        int ss0 = k * Sc, ss1 = min(ss0 + Sc, W);
        for (int s = ss0; s < ss1; ++s) {
            x = s_bp[(n - 1 - s) * TT + x];
            s_tags[n - 2 - s] = x;
        }
    }
    __syncthreads();

    // ---- coalesced output write ----
    int* orow = out + b * LL;
    #pragma unroll
    for (int k = 0; k < LL / 256; ++k) orow[tid + 256 * k] = s_tags[tid + 256 * k];
}

extern "C" void kernel_launch(void* const* d_in, const int* in_sizes, int n_in,
                              void* d_out, int out_size, void* d_ws, size_t ws_size,
                              hipStream_t stream) {
    const float* feats = (const float*)d_in[0];
    const int*   mask  = (const int*)d_in[1];
    const float* trans = (const float*)d_in[2];
    int* out = (int*)d_out;
    viterbi_kernel<<<dim3(BB), dim3(256), 0, stream>>>(feats, mask, trans, out);
}